// Round 4
// baseline (179.241 us; speedup 1.0000x reference)
//
#include <hip/hip_runtime.h>

#define N_POINTS 1440
#define N_INT    4000
#define N_GRID   4096
#define BLOCK    256

#define NSEG     4                          // along-ray segments per ray
#define SEG_LEN  (N_INT / NSEG)             // 1000 samples per segment
#define RPC      4                          // rays per cluster (adjacent thetas)
#define NCLUST   (N_POINTS / RPC)           // 360 clusters
#define K_FULL   15                         // full k-batches (64 samples apart)
#define TAIL_Q   (SEG_LEN - K_FULL * 64)    // 40: k=15 valid for q < 40

#define DIAG_REP 8                          // diagnostic work multiplier
#define DIAG_OFF (2u << 20)                 // 8 MB (in floats) dead sink in ws

// ---------------------------------------------------------------------------
// DIAGNOSTIC kernel (this round only): identical body to the real partial
// kernel, repeated DIAG_REP times with opaque asm barriers so the compiler
// cannot hoist addresses or CSE loads across reps. Purpose: a single dispatch
// long enough (8x) to enter the harness's top-5 counter table, yielding the
// partial kernel's true per-iteration duration (dur/8), its cold HBM traffic
// (FETCH_SIZE: rep 1 is post-poison cold, reps 2-8 are L3-warm), and
// VALUBusy -- the three numbers that decide issue-bound vs gather-bound vs
// harness-floor. Writes to a dead region of ws; results unused.
// ---------------------------------------------------------------------------
__global__ __launch_bounds__(BLOCK, 6) void wavefront_diag_kernel(
    const float* __restrict__ xp,
    const float* __restrict__ yp,
    const float* __restrict__ SoS,
    const float* __restrict__ thetas,
    const float* __restrict__ x0p,
    const float* __restrict__ y0p,
    const float* __restrict__ dxp,
    const float* __restrict__ dyp,
    const float* __restrict__ Rp,
    const float* __restrict__ v0p,
    float* __restrict__ ws)
{
    const int b = blockIdx.x;
    const int c = b >> 2;
    const int S = ((b & 3) + c) & 3;
    const int t = threadIdx.x;
    const int r = t & 3;
    const int q = t >> 2;

    const int p = c * RPC + r;

    const float x  = xp[0];
    const float y  = yp[0];
    const float x0 = x0p[0];
    const float y0 = y0p[0];
    const float dx = dxp[0];
    const float dy = dyp[0];
    const float Rb = Rp[0];
    const float v0 = v0p[0];

    const float theta = thetas[p];

    const float rr  = sqrtf(x * x + y * y);
    const float phi = atan2f(x, y);
    const float st  = sinf(theta);
    const float ct  = cosf(theta);

    const float sv    = rr * sinf(theta - phi);
    const float arg   = fmaxf(Rb * Rb - sv * sv, 0.0f);
    const float sq    = sqrtf(arg);
    const float l_in  = sq + rr * cosf(theta - phi);
    const float l_out = 2.0f * sq * (cosf(phi - theta) >= 0.0f ? 1.0f : 0.0f);
    const float l     = (rr < Rb) ? l_in : l_out;

    const float ds = 1.0f / 3999.0f;
    const float Ax = (x - x0) / dx;
    const float Ay = (y - y0) / dy;
    const float bx = l * st / dx * ds;
    const float by = l * ct / dy * ds;

    const int   jb  = S * SEG_LEN + q;
    float fx0 = fmaf(-bx, (float)jb, Ax + 0.5f);
    float gy0 = fmaf( by, (float)jb, 4096.5f - Ay);
    const float dX  = -bx * 64.0f;
    const float dY  =  by * 64.0f;

    const bool has_tail = (q < TAIL_Q);

    float accD = 0.0f;
#pragma unroll 1
    for (int rep = 0; rep < DIAG_REP; ++rep) {
        // Opaque no-ops: force per-rep address recomputation (matches the
        // real kernel's per-iteration addr cost) and forbid cross-rep CSE.
        asm volatile("" : "+v"(fx0), "+v"(gy0));

        float rv[16];
#pragma unroll
        for (int k = 0; k < K_FULL; ++k) {
            const float kf = (float)k;
            const int xi  = (int)fmaf(kf, dX, fx0);
            const int row = (int)fmaf(kf, dY, gy0);
            rv[k] = SoS[(row << 12) + xi];
        }
        if (has_tail) {
            const float kf = (float)K_FULL;
            const int xi  = (int)fmaf(kf, dX, fx0);
            const int row = (int)fmaf(kf, dY, gy0);
            rv[15] = SoS[(row << 12) + xi];
        }

        float accR = 0.0f;
#pragma unroll
        for (int k = 0; k < K_FULL; ++k)
            accR += __builtin_amdgcn_rcpf(rv[k]);
        float n = 15.0f;
        if (has_tail) { accR += __builtin_amdgcn_rcpf(rv[15]); n = 16.0f; }

        accD += fmaf(-v0, accR, n);
        asm volatile("" ::: "memory");   // loads must repeat next rep
    }

    accD += __shfl_xor(accD, 4, 64);
    accD += __shfl_xor(accD, 8, 64);
    accD += __shfl_xor(accD, 16, 64);
    accD += __shfl_xor(accD, 32, 64);

    __shared__ float wsum[4][4];
    if ((t & 63) < 4) wsum[t >> 6][r] = accD;
    __syncthreads();
    if (t < 4) {
        const float tot = (wsum[0][t] + wsum[1][t]) + (wsum[2][t] + wsum[3][t]);
        ws[DIAG_OFF + (c * RPC + t) * NSEG + S] = tot;   // dead sink
    }
}

// ---------------------------------------------------------------------------
// REAL pipeline: identical to R3 (passed, absmax 7.7e-7).
// ---------------------------------------------------------------------------
__global__ __launch_bounds__(BLOCK, 6) void wavefront_partial_kernel(
    const float* __restrict__ xp,
    const float* __restrict__ yp,
    const float* __restrict__ SoS,
    const float* __restrict__ thetas,
    const float* __restrict__ x0p,
    const float* __restrict__ y0p,
    const float* __restrict__ dxp,
    const float* __restrict__ dyp,
    const float* __restrict__ Rp,
    const float* __restrict__ v0p,
    float* __restrict__ ws)
{
    const int b = blockIdx.x;
    const int c = b >> 2;                 // cluster index 0..359
    const int S = ((b & 3) + c) & 3;      // segment, rotated for radial balance
    const int t = threadIdx.x;
    const int r = t & 3;                  // ray within cluster
    const int q = t >> 2;                 // sample slot (0..63)

    const int p = c * RPC + r;

    const float x  = xp[0];
    const float y  = yp[0];
    const float x0 = x0p[0];
    const float y0 = y0p[0];
    const float dx = dxp[0];
    const float dy = dyp[0];
    const float Rb = Rp[0];
    const float v0 = v0p[0];

    const float theta = thetas[p];

    const float rr  = sqrtf(x * x + y * y);
    const float phi = atan2f(x, y);              // reference uses atan2(x, y)
    const float st  = sinf(theta);
    const float ct  = cosf(theta);

    const float sv    = rr * sinf(theta - phi);
    const float arg   = fmaxf(Rb * Rb - sv * sv, 0.0f);
    const float sq    = sqrtf(arg);
    const float l_in  = sq + rr * cosf(theta - phi);
    const float l_out = 2.0f * sq * (cosf(phi - theta) >= 0.0f ? 1.0f : 0.0f);
    const float l     = (rr < Rb) ? l_in : l_out;

    const float ds = 1.0f / 3999.0f;
    const float Ax = (x - x0) / dx;
    const float Ay = (y - y0) / dy;
    const float bx = l * st / dx * ds;
    const float by = l * ct / dy * ds;

    const int   jb  = S * SEG_LEN + q;           // base sample index (k=0)
    const float fx0 = fmaf(-bx, (float)jb, Ax + 0.5f);
    const float gy0 = fmaf( by, (float)jb, 4096.5f - Ay);
    const float dX  = -bx * 64.0f;               // per-k deltas (64 samples)
    const float dY  =  by * 64.0f;

    const bool has_tail = (q < TAIL_Q);

    float rv[16];
#pragma unroll
    for (int k = 0; k < K_FULL; ++k) {
        const float kf = (float)k;
        const int xi  = (int)fmaf(kf, dX, fx0);
        const int row = (int)fmaf(kf, dY, gy0);
        rv[k] = SoS[(row << 12) + xi];
    }
    if (has_tail) {
        const float kf = (float)K_FULL;
        const int xi  = (int)fmaf(kf, dX, fx0);
        const int row = (int)fmaf(kf, dY, gy0);
        rv[15] = SoS[(row << 12) + xi];
    }

    float accR = 0.0f;
#pragma unroll
    for (int k = 0; k < K_FULL; ++k)
        accR += __builtin_amdgcn_rcpf(rv[k]);
    float n = 15.0f;
    if (has_tail) { accR += __builtin_amdgcn_rcpf(rv[15]); n = 16.0f; }

    if (S == 0 && q == 0) {
        accR -= 0.5f * __builtin_amdgcn_rcpf(rv[0]);
        n -= 0.5f;
    }
    if (S == NSEG - 1 && q == TAIL_Q - 1) {
        accR -= 0.5f * __builtin_amdgcn_rcpf(rv[15]);
        n -= 0.5f;
    }

    float acc = fmaf(-v0, accR, n);

    acc += __shfl_xor(acc, 4, 64);
    acc += __shfl_xor(acc, 8, 64);
    acc += __shfl_xor(acc, 16, 64);
    acc += __shfl_xor(acc, 32, 64);

    __shared__ float wsum[4][4];
    if ((t & 63) < 4) wsum[t >> 6][r] = acc;
    __syncthreads();
    if (t < 4) {
        const float tot = (wsum[0][t] + wsum[1][t]) + (wsum[2][t] + wsum[3][t]);
        ws[(c * RPC + t) * NSEG + S] = tot;   // partials[ray][segment]
    }
}

__global__ __launch_bounds__(BLOCK) void wavefront_combine_kernel(
    const float* __restrict__ xp,
    const float* __restrict__ yp,
    const float* __restrict__ thetas,
    const float* __restrict__ Rp,
    const float* __restrict__ ws,
    float* __restrict__ out)
{
    const int p = blockIdx.x * BLOCK + threadIdx.x;
    if (p >= N_POINTS) return;

    const float x  = xp[0];
    const float y  = yp[0];
    const float Rb = Rp[0];
    const float theta = thetas[p];

    const float rr  = sqrtf(x * x + y * y);
    const float phi = atan2f(x, y);
    const float sv    = rr * sinf(theta - phi);
    const float arg   = fmaxf(Rb * Rb - sv * sv, 0.0f);
    const float sq    = sqrtf(arg);
    const float l_in  = sq + rr * cosf(theta - phi);
    const float l_out = 2.0f * sq * (cosf(phi - theta) >= 0.0f ? 1.0f : 0.0f);
    const float l     = (rr < Rb) ? l_in : l_out;

    const float4 a = *(const float4*)(ws + p * NSEG);   // 16B per ray
    const float tot = (a.x + a.y) + (a.z + a.w);

    out[p] = theta;                                 // output 0: thetas
    out[N_POINTS + p] = l * (1.0f / 3999.0f) * tot; // output 1: wf
}

extern "C" void kernel_launch(void* const* d_in, const int* in_sizes, int n_in,
                              void* d_out, int out_size, void* d_ws, size_t ws_size,
                              hipStream_t stream) {
    (void)in_sizes; (void)n_in; (void)out_size;

    const float* xp     = (const float*)d_in[0];
    const float* yp     = (const float*)d_in[1];
    const float* SoS    = (const float*)d_in[2];
    const float* thetas = (const float*)d_in[3];
    // d_in[4] (steps) unused: steps == linspace(0,1,4000), used analytically.
    const float* x0p    = (const float*)d_in[5];
    const float* y0p    = (const float*)d_in[6];
    const float* dxp    = (const float*)d_in[7];
    const float* dyp    = (const float*)d_in[8];
    const float* Rp     = (const float*)d_in[9];
    const float* v0p    = (const float*)d_in[10];

    float* ws  = (float*)d_ws;
    float* out = (float*)d_out;

    // Diagnostic dispatch (this round only): needs ws >= 8 MB + sink.
    if (ws_size >= (size_t)(DIAG_OFF + N_POINTS * NSEG) * sizeof(float) + 64) {
        wavefront_diag_kernel<<<NCLUST * NSEG, BLOCK, 0, stream>>>(
            xp, yp, SoS, thetas, x0p, y0p, dxp, dyp, Rp, v0p, ws);
    }

    wavefront_partial_kernel<<<NCLUST * NSEG, BLOCK, 0, stream>>>(
        xp, yp, SoS, thetas, x0p, y0p, dxp, dyp, Rp, v0p, ws);
    wavefront_combine_kernel<<<(N_POINTS + BLOCK - 1) / BLOCK, BLOCK, 0, stream>>>(
        xp, yp, thetas, Rp, ws, out);
}

// Round 5
// 125.027 us; speedup vs baseline: 1.4336x; 1.4336x over previous
//
#include <hip/hip_runtime.h>

#define N_POINTS 1440
#define N_INT    4000
#define N_GRID   4096
#define BLOCK    256

#define K_FULL   15                         // full k-batches (256 samples apart)
#define TAIL_T   (N_INT - K_FULL * BLOCK)   // 160: k=15 valid for t < 160

// Single-kernel version. R4's diagnostic (8x-repeated body in the counter
// table) settled the model:
//   - warm pass ~8.5 us == L1 distinct-line serialization floor (~3.6M line
//     requests / 256 CU at ~1 line/cyc) + 20% VALU. NOT issue-bound.
//   - cold pass ~16 us == 93 MB HBM fetch (harness poison fills thrash the
//     256MB L3 every iteration, so the gather always runs cold). That fetch
//     was invariant across four different lane layouts (R0-R3): it is the
//     disk footprint at fetch granularity -- a floor.
// The only remaining ownable time was pipeline structure: the combine
// dispatch, its launch gap, and the ws round-trip. This version is one
// dispatch: block = 1 ray, thread t sums samples j = t + 256k (k=0..15,
// k=15 only for t<160), block-reduces, thread 0 writes out directly.
__global__ __launch_bounds__(BLOCK, 6) void wavefront_sos_kernel(
    const float* __restrict__ xp,
    const float* __restrict__ yp,
    const float* __restrict__ SoS,
    const float* __restrict__ thetas,
    const float* __restrict__ x0p,
    const float* __restrict__ y0p,
    const float* __restrict__ dxp,
    const float* __restrict__ dyp,
    const float* __restrict__ Rp,
    const float* __restrict__ v0p,
    float* __restrict__ out)
{
    const int p = blockIdx.x;             // one ray per block
    const int t = threadIdx.x;

    const float x  = xp[0];
    const float y  = yp[0];
    const float x0 = x0p[0];
    const float y0 = y0p[0];
    const float dx = dxp[0];
    const float dy = dyp[0];
    const float Rb = Rp[0];
    const float v0 = v0p[0];

    const float theta = thetas[p];

    // Per-ray geometry (redundant across threads; negligible).
    const float rr  = sqrtf(x * x + y * y);
    const float phi = atan2f(x, y);              // reference uses atan2(x, y)
    const float st  = sinf(theta);
    const float ct  = cosf(theta);

    const float sv    = rr * sinf(theta - phi);
    const float arg   = fmaxf(Rb * Rb - sv * sv, 0.0f);
    const float sq    = sqrtf(arg);
    const float l_in  = sq + rr * cosf(theta - phi);
    const float l_out = 2.0f * sq * (cosf(phi - theta) >= 0.0f ? 1.0f : 0.0f);
    const float l     = (rr < Rb) ? l_in : l_out;

    // fx(j) = Ax - bx*j ; fy(j) = Ay - by*j   (j = 0..3999)
    // xi  = rint(fx)        ~= trunc(fx + 0.5)           [positive]
    // row = 4096 - rint(fy) ~= trunc(4096.5 - fy)        [folds the wrap]
    const float ds = 1.0f / 3999.0f;
    const float Ax = (x - x0) / dx;
    const float Ay = (y - y0) / dy;
    const float bx = l * st / dx * ds;
    const float by = l * ct / dy * ds;

    const float fx0 = fmaf(-bx, (float)t, Ax + 0.5f);
    const float gy0 = fmaf( by, (float)t, 4096.5f - Ay);
    const float dX  = -bx * 256.0f;              // per-k deltas (256 samples)
    const float dY  =  by * 256.0f;

    const bool has_tail = (t < TAIL_T);

    // ---- phase 1: compute indices, issue all 16 loads (deep MLP) ----
    float rv[16];
#pragma unroll
    for (int k = 0; k < K_FULL; ++k) {
        const float kf = (float)k;
        const int xi  = (int)fmaf(kf, dX, fx0);
        const int row = (int)fmaf(kf, dY, gy0);
        rv[k] = SoS[(row << 12) + xi];
    }
    if (has_tail) {
        const float kf = (float)K_FULL;
        const int xi  = (int)fmaf(kf, dX, fx0);
        const int row = (int)fmaf(kf, dY, gy0);
        rv[15] = SoS[(row << 12) + xi];
    }

    // ---- phase 2: sum reciprocals; contribution = n - v0*sum(rcp) ----
    float accR = 0.0f;
#pragma unroll
    for (int k = 0; k < K_FULL; ++k)
        accR += __builtin_amdgcn_rcpf(rv[k]);
    float n = 15.0f;
    if (has_tail) { accR += __builtin_amdgcn_rcpf(rv[15]); n = 16.0f; }

    // Trapezoid end weights: j=0 is (t=0,k=0); j=3999 = 15*256+159 is
    // (t=159,k=15) -- the last valid tail slot.
    if (t == 0) {
        accR -= 0.5f * __builtin_amdgcn_rcpf(rv[0]);
        n -= 0.5f;
    }
    if (t == TAIL_T - 1) {
        accR -= 0.5f * __builtin_amdgcn_rcpf(rv[15]);
        n -= 0.5f;
    }

    float acc = fmaf(-v0, accR, n);

    // Block reduction: wave64 butterfly, then LDS across the 4 waves.
    acc += __shfl_xor(acc, 1, 64);
    acc += __shfl_xor(acc, 2, 64);
    acc += __shfl_xor(acc, 4, 64);
    acc += __shfl_xor(acc, 8, 64);
    acc += __shfl_xor(acc, 16, 64);
    acc += __shfl_xor(acc, 32, 64);

    __shared__ float wave_sums[4];
    if ((t & 63) == 0) wave_sums[t >> 6] = acc;
    __syncthreads();

    if (t == 0) {
        const float total = (wave_sums[0] + wave_sums[1])
                          + (wave_sums[2] + wave_sums[3]);
        out[p] = theta;                          // output 0: thetas
        out[N_POINTS + p] = l * ds * total;      // output 1: wf
    }
}

extern "C" void kernel_launch(void* const* d_in, const int* in_sizes, int n_in,
                              void* d_out, int out_size, void* d_ws, size_t ws_size,
                              hipStream_t stream) {
    (void)in_sizes; (void)n_in; (void)out_size; (void)d_ws; (void)ws_size;

    const float* xp     = (const float*)d_in[0];
    const float* yp     = (const float*)d_in[1];
    const float* SoS    = (const float*)d_in[2];
    const float* thetas = (const float*)d_in[3];
    // d_in[4] (steps) unused: steps == linspace(0,1,4000), used analytically.
    const float* x0p    = (const float*)d_in[5];
    const float* y0p    = (const float*)d_in[6];
    const float* dxp    = (const float*)d_in[7];
    const float* dyp    = (const float*)d_in[8];
    const float* Rp     = (const float*)d_in[9];
    const float* v0p    = (const float*)d_in[10];

    float* out = (float*)d_out;

    wavefront_sos_kernel<<<N_POINTS, BLOCK, 0, stream>>>(
        xp, yp, SoS, thetas, x0p, y0p, dxp, dyp, Rp, v0p, out);
}